// Round 11
// baseline (225.047 us; speedup 1.0000x reference)
//
#include <hip/hip_runtime.h>
#include <math.h>

#define B_  8
#define R_  64
#define C_  256
#define NH_ 8
#define N_  4096
#define HD_ 32
#define LDP 260   // padded LDS row stride (floats)

__device__ __forceinline__ float softplus_rcp(float s) {
    return 1.f / __logf(1.f + __expf(s));     // 1/softplus, fast intrinsics
}

// ---------------------------------------------------------------------------
// pub_barrier: barrier that publishes LDS writes WITHOUT draining vmcnt.
// hipcc's __syncthreads emits "s_waitcnt vmcnt(0) lgkmcnt(0); s_barrier",
// force-completing every in-flight global load at every barrier -- this is
// why every register-prefetch pipeline in R3-R8 ran identically to the
// unpipelined kernel. Here: lgkmcnt(0) ("memory"-ordered) makes ds_writes
// visible, raw s_barrier syncs, sched_barrier(0) stops the scheduler from
// hoisting the following ds_reads above the barrier. In-flight global->reg
// loads stay outstanding; the compiler still inserts counted vmcnt waits at
// first register use. (T4 counted-wait technique, guide-verified on gfx950.)
// ---------------------------------------------------------------------------
__device__ __forceinline__ void pub_barrier() {
    asm volatile("s_waitcnt lgkmcnt(0)" ::: "memory");
    __builtin_amdgcn_s_barrier();
    __builtin_amdgcn_sched_barrier(0);
}

// ---------------------------------------------------------------------------
// Kernel NB11: R4's NB4 (measured-best 223.07) with pub_barrier replacing
// __syncthreads in the pipeline. Schedule per iter:
//   COMP(t) | PROC(t+1) | LOAD(t+2) | pub_barrier
// LOAD(t+2)'s 16 float4 loads now genuinely survive the barrier and land
// under the next COMP+PROC (~2000cy of cover) instead of being drained
// ~0cy after issue. All cross-wave data is LDS (lgkmcnt-published);
// staging regs are private. Buffer hazards identical to R4.
// ---------------------------------------------------------------------------
__global__ __launch_bounds__(256) void kernelNB11(
        const float* __restrict__ qkv, const float* __restrict__ pos,
        const float* __restrict__ scale,
        float* __restrict__ qs_arr, float* __restrict__ part,
        float* __restrict__ kspart) {
    __shared__ float smem[16896];           // 67.6 KB -> 2 blocks/CU
    float* rsc_s = smem + 16640;            // [256]

    const int t    = threadIdx.x;
    const int wave = t >> 6, lane = t & 63;
    const int tk   = lane >> 4;             // token sub-group within wave 0..3
    const int lr   = lane & 15;             // lane within token's 16-lane group
    const int blk  = blockIdx.x;
    const int tok0 = blk * 64;
    const int row  = wave * 4 + tk;         // 0..15: this lane's row in a tile

    rsc_s[t] = softplus_rcp(scale[t]);

    const size_t qbase = (size_t)tok0 * C_;
    const size_t koff  = (size_t)B_ * N_ * C_;
    const size_t voff  = (size_t)2 * B_ * N_ * C_;

    const int h  = t >> 5;                  // head 0..7
    const int l  = t & 31;
    const int cg = l & 7;                   // c sub-tile: cg*4 .. cg*4+3
    const int dg = l >> 3;                  // d sub-tile: dg*8 .. dg*8+7

    float acc[4][8];
    #pragma unroll
    for (int ii = 0; ii < 4; ii++)
        #pragma unroll
        for (int jj = 0; jj < 8; jj++) acc[ii][jj] = 0.f;
    float ksp[4] = {0.f, 0.f, 0.f, 0.f};    // ksum piggyback (dg==0 writes)

    float4 sq[4], sk[4], sv[4], sp[4];      // register staging for one tile

    auto LOAD = [&](int tt) {
        const int    nrow = tt * 16 + row;
        const size_t off  = qbase + (size_t)nrow * C_;
        const size_t poff = (size_t)((tok0 + nrow) & (N_ - 1)) * C_;
        #pragma unroll
        for (int j = 0; j < 4; j++) {
            const int c = j * 64 + lr * 4;
            sq[j] = *(const float4*)(qkv + off + c);
            sk[j] = *(const float4*)(qkv + koff + off + c);
            sv[j] = *(const float4*)(qkv + voff + off + c);
            sp[j] = *(const float4*)(pos + poff + c);
        }
    };

    auto PROC = [&](int tt) {
        float* kf_s = (tt & 1) ? smem + 4160  : smem;
        float* v_s  = (tt & 1) ? smem + 12480 : smem + 8320;
        const int tok = tok0 + tt * 16 + row;
        float kc[16];
        float sq2 = 0.f, sq6 = 0.f, sk2 = 0.f, sk6 = 0.f;
        #pragma unroll
        for (int j = 0; j < 4; j++) {
            const int c = j * 64 + lr * 4;
            *(float4*)&v_s[row * LDP + c] = sv[j];
            const float qa[4] = {sq[j].x, sq[j].y, sq[j].z, sq[j].w};
            const float ka[4] = {sk[j].x, sk[j].y, sk[j].z, sk[j].w};
            const float pa[4] = {sp[j].x, sp[j].y, sp[j].z, sp[j].w};
            #pragma unroll
            for (int e = 0; e < 4; e++) {
                const float r  = rsc_s[c + e];
                const float qv = (fmaxf(qa[e], 0.f) + 1e-6f) * r;
                const float kw = (fmaxf(ka[e] + pa[e], 0.f) + 1e-6f) * r;
                sq2 += qv * qv;  sk2 += kw * kw;
                const float q3 = qv * qv * qv, k3 = kw * kw * kw;
                sq6 += q3 * q3;  sk6 += k3 * k3;
                kc[j * 4 + e] = k3;
            }
        }
        #pragma unroll
        for (int m = 1; m < 16; m <<= 1) {       // 4-step 16-lane butterfly
            sq2 += __shfl_xor(sq2, m, 64);
            sq6 += __shfl_xor(sq6, m, 64);
            sk2 += __shfl_xor(sk2, m, 64);
            sk6 += __shfl_xor(sk6, m, 64);
        }
        if (lr == 0) qs_arr[tok] = sqrtf(sq2) * rsqrtf(sq6);
        const float ks = sqrtf(sk2) * rsqrtf(sk6);
        #pragma unroll
        for (int j = 0; j < 4; j++) {
            const float4 kf4 = make_float4(kc[j*4+0] * ks, kc[j*4+1] * ks,
                                           kc[j*4+2] * ks, kc[j*4+3] * ks);
            *(float4*)&kf_s[row * LDP + j * 64 + lr * 4] = kf4;
        }
    };

    auto COMP = [&](int tt) {
        const float* kf_s = (tt & 1) ? smem + 4160  : smem;
        const float* v_s  = (tt & 1) ? smem + 12480 : smem + 8320;
        const float* kfp = kf_s + h * HD_ + cg * 4;
        const float* vp  = v_s  + h * HD_ + dg * 8;
        #pragma unroll 4
        for (int nl = 0; nl < 16; nl++) {
            const float4 kr = *(const float4*)(kfp + nl * LDP);
            const float4 va = *(const float4*)(vp  + nl * LDP);
            const float4 vb = *(const float4*)(vp  + nl * LDP + 4);
            ksp[0] += kr.x;  ksp[1] += kr.y;
            ksp[2] += kr.z;  ksp[3] += kr.w;
            const float kk[4] = {kr.x, kr.y, kr.z, kr.w};
            const float vv[8] = {va.x, va.y, va.z, va.w,
                                 vb.x, vb.y, vb.z, vb.w};
            #pragma unroll
            for (int ii = 0; ii < 4; ii++)
                #pragma unroll
                for (int jj = 0; jj < 8; jj++)
                    acc[ii][jj] = fmaf(kk[ii], vv[jj], acc[ii][jj]);
        }
    };

    LOAD(0);
    pub_barrier();                   // rsc_s published; LOAD(0) stays in flight
    PROC(0);
    LOAD(1);
    pub_barrier();                   // kf/v(0) published; LOAD(1) in flight
    #pragma unroll
    for (int tt = 0; tt < 4; tt++) {
        COMP(tt);
        if (tt < 3) PROC(tt + 1);
        if (tt < 2) LOAD(tt + 2);
        if (tt < 3) pub_barrier();   // tile t+1 published; LOAD(t+2) in flight
    }
    pub_barrier();                   // COMP(3) reads done before staging reuse

    // ---- epilogue: stage kv partial in LDS, write coalesced (no atomics) --
    #pragma unroll
    for (int ii = 0; ii < 4; ii++) {
        const float4 a = make_float4(acc[ii][0], acc[ii][1], acc[ii][2], acc[ii][3]);
        const float4 b = make_float4(acc[ii][4], acc[ii][5], acc[ii][6], acc[ii][7]);
        const int base = h * 1024 + (cg * 4 + ii) * 32 + dg * 8;
        *(float4*)&smem[base]     = a;
        *(float4*)&smem[base + 4] = b;
    }
    if (dg == 0)                              // ksum partial, channel h*32+cg*4
        *(float4*)&kspart[(size_t)blk * 256 + h * 32 + cg * 4] =
            make_float4(ksp[0], ksp[1], ksp[2], ksp[3]);
    __syncthreads();                          // once per kernel; plain is fine
    float* pdst = part + (size_t)blk * 8192;
    #pragma unroll
    for (int i = 0; i < 8; i++)
        *(float4*)&pdst[i * 1024 + t * 4] = *(const float4*)&smem[i * 1024 + t * 4];
}

// ---------------------------------------------------------------------------
// Kernel R: reduce 64 per-block partials -> kv_ws[64][1024], ksum_ws[64][32].
// Grid 256 = 64 bh x 4 quarters; partials are L2/L3-resident (just written).
// Writes kv_ws/ksum_ws destructively (no memset needed). [R4 verbatim]
// ---------------------------------------------------------------------------
__global__ __launch_bounds__(256) void kernelR(
        const float* __restrict__ part, const float* __restrict__ kspart,
        float* __restrict__ kv_ws, float* __restrict__ ksum_ws) {
    const int t  = threadIdx.x;
    const int bh = blockIdx.x >> 2, q = blockIdx.x & 3;
    const int b  = bh >> 3, h = bh & 7;

    const float* p = part + (size_t)(b * 64) * 8192 + h * 1024 + q * 256 + t;
    float s = 0.f;
    #pragma unroll 4
    for (int j = 0; j < 64; j++) s += p[(size_t)j * 8192];
    kv_ws[bh * 1024 + q * 256 + t] = s;

    if (q == 0 && t < 32) {
        const float* kp = kspart + (size_t)(b * 64) * 256 + h * 32 + t;
        float s2 = 0.f;
        #pragma unroll 8
        for (int j = 0; j < 64; j++) s2 += kp[(size_t)j * 256];
        ksum_ws[bh * 32 + t] = s2;
    }
}

// ---------------------------------------------------------------------------
// Kernel CD6: CD5 (R10) with pub_barrier on the two phase barriers. With
// __syncthreads, R10's q-prefetch was provably neutral: the vmcnt(0) drain
// at the first barrier force-completed the prefetch anyway. With pub_barrier
// the q/qs loads issued at kernel start stay in flight under the halo-stage
// and conv phases (~2200cy of cover) and are consumed by counted vmcnt waits
// at the attn phase. Everything else identical to the verified CD2/CD5.
// ---------------------------------------------------------------------------
__global__ __launch_bounds__(256) void kernelCD6(
        const float* __restrict__ qkv, const float* __restrict__ qs_arr,
        const float* __restrict__ kv_ws, const float* __restrict__ ksum_ws,
        const float* __restrict__ scale,
        const float* __restrict__ w_v,  const float* __restrict__ b_v,
        const float* __restrict__ w_dwc, const float* __restrict__ b_dwc,
        float* __restrict__ out) {
    __shared__ float v_s[20 * 20 * 32];   // 51.2 KB; reused as conv_s (256*33)
    __shared__ float kv_s[1024];
    __shared__ float ks_s[32];
    __shared__ float rsc_s[32];
    const int t    = threadIdx.x;
    const int tile = blockIdx.x;
    const int h    = blockIdx.y;
    const int b    = blockIdx.z;
    const int ty0  = (tile >> 2) * 16, tx0 = (tile & 3) * 16;
    const int bh   = b * NH_ + h;

    ((float4*)kv_s)[t] = ((const float4*)(kv_ws + (size_t)bh * 1024))[t];
    if (t < 32) {
        ks_s[t]  = ksum_ws[bh * HD_ + t];
        rsc_s[t] = softplus_rcp(scale[h * HD_ + t]);
    }

    const float* vb = qkv + (size_t)2 * B_ * N_ * C_ + (size_t)b * N_ * C_ + h * HD_;
    #pragma unroll
    for (int i = 0; i < 13; i++) {
        const int idx = i * 256 + t;
        if (idx < 3200) {
            const int pix = idx >> 3, d4 = (idx & 7) * 4;
            const int yy = pix / 20, xx = pix - yy * 20;
            const int gy = ty0 + yy - 2, gx = tx0 + xx - 2;
            float4 val = make_float4(0.f, 0.f, 0.f, 0.f);
            if (gy >= 0 && gy < R_ && gx >= 0 && gx < R_)
                val = *(const float4*)(vb + (size_t)(gy * R_ + gx) * C_ + d4);
            *(float4*)&v_s[pix * 32 + d4] = val;
        }
    }

    // ---- prefetch q + qs: stays in flight through conv with pub_barrier ---
    const int tyy = t >> 4, txx = t & 15;
    const int tok = b * N_ + (ty0 + tyy) * R_ + (tx0 + txx);
    float qreg[32];
    {
        const float4* qsrc = (const float4*)(qkv + (size_t)tok * C_ + h * HD_);
        #pragma unroll
        for (int i = 0; i < 8; i++) ((float4*)qreg)[i] = qsrc[i];
    }
    const float qs = qs_arr[tok];

    const int c  = t & 31, pg = t >> 5;
    float wv[9], wd[25];
    {
        const float* wvp = w_v + (size_t)(h * HD_ + c) * 9;
        const float* wdp = w_dwc + (size_t)c * 25;
        #pragma unroll
        for (int i = 0; i < 9; i++)  wv[i] = wvp[i];
        #pragma unroll
        for (int i = 0; i < 25; i++) wd[i] = wdp[i];
    }
    const float bias = b_v[h * HD_ + c] + b_dwc[c];
    pub_barrier();                  // halo/kv/ks published; q-loads in flight

    // ---- conv phase: thread = (channel c, 2 tile rows), ring window ----
    float res[32];
    #pragma unroll
    for (int r2 = 0; r2 < 2; r2++) {
        const int ty = pg * 2 + r2;
        float win[5][5];
        #pragma unroll
        for (int j = 0; j < 5; j++)
            #pragma unroll
            for (int i = 0; i < 5; i++)
                win[j][i] = v_s[((ty + i) * 20 + j) * 32 + c];
        #pragma unroll
        for (int tx = 0; tx < 16; tx++) {
            float a = bias;
            #pragma unroll
            for (int j = 0; j < 5; j++) {
                const int slot = (tx + j) % 5;
                #pragma unroll
                for (int i = 0; i < 5; i++)
                    a = fmaf(wd[i * 5 + j], win[slot][i], a);
            }
            #pragma unroll
            for (int j = 1; j < 4; j++) {
                const int slot = (tx + j) % 5;
                #pragma unroll
                for (int i = 1; i < 4; i++)
                    a = fmaf(wv[(i - 1) * 3 + (j - 1)], win[slot][i], a);
            }
            res[r2 * 16 + tx] = a;
            if (tx < 15) {
                const int slot = tx % 5;
                #pragma unroll
                for (int i = 0; i < 5; i++)
                    win[slot][i] = v_s[((ty + i) * 20 + (tx + 5)) * 32 + c];
            }
        }
    }
    pub_barrier();                  // conv reads of v_s done before re-stage
    #pragma unroll
    for (int r2 = 0; r2 < 2; r2++)
        #pragma unroll
        for (int tx = 0; tx < 16; tx++)
            v_s[((pg * 2 + r2) * 16 + tx) * 33 + c] = res[r2 * 16 + tx];
    pub_barrier();                  // res re-stage published

    // ---- attention phase: thread = pixel; q already in registers ----
    {
        #pragma unroll
        for (int i = 0; i < 32; i++) {
            const float r = (fmaxf(qreg[i], 0.f) + 1e-6f) * rsc_s[i];
            qreg[i] = r * r * r * qs;
        }

        float denom = 1e-6f;
        #pragma unroll
        for (int cc = 0; cc < 32; cc++) denom = fmaf(qreg[cc], ks_s[cc], denom);
        const float z = 1.f / denom;

        float o[32];
        #pragma unroll
        for (int i = 0; i < 32; i++) o[i] = 0.f;
        #pragma unroll
        for (int cc = 0; cc < 32; cc++) {
            const float qc = qreg[cc];
            #pragma unroll
            for (int d = 0; d < 32; d++)
                o[d] = fmaf(qc, kv_s[cc * 32 + d], o[d]);
        }
        float4* dst = (float4*)(out + (size_t)tok * C_ + h * HD_);
        #pragma unroll
        for (int i = 0; i < 8; i++) {
            float4 v4;
            v4.x = fmaf(o[i*4+0], z, v_s[t * 33 + i*4+0]);
            v4.y = fmaf(o[i*4+1], z, v_s[t * 33 + i*4+1]);
            v4.z = fmaf(o[i*4+2], z, v_s[t * 33 + i*4+2]);
            v4.w = fmaf(o[i*4+3], z, v_s[t * 33 + i*4+3]);
            dst[i] = v4;
        }
    }
}

// ---------------------------------------------------------------------------
extern "C" void kernel_launch(void* const* d_in, const int* in_sizes, int n_in,
                              void* d_out, int out_size, void* d_ws, size_t ws_size,
                              hipStream_t stream) {
    const float* qkv   = (const float*)d_in[0];
    const float* pos   = (const float*)d_in[1];
    const float* scale = (const float*)d_in[2];
    const float* w_v   = (const float*)d_in[3];
    const float* b_v   = (const float*)d_in[4];
    const float* w_dwc = (const float*)d_in[5];
    const float* b_dwc = (const float*)d_in[6];
    float* out = (float*)d_out;

    float* qs_arr  = (float*)d_ws;                       // 32768 floats
    float* part    = qs_arr + (size_t)B_ * N_;           // 512*8192 floats
    float* kspart  = part + (size_t)512 * 8192;          // 512*256 floats
    float* kv_ws   = kspart + (size_t)512 * 256;         // 64*1024 floats
    float* ksum_ws = kv_ws + 64 * 1024;                  // 64*32 floats

    kernelNB11<<<dim3(512), 256, 0, stream>>>(qkv, pos, scale, qs_arr, part, kspart);
    kernelR<<<dim3(256), 256, 0, stream>>>(part, kspart, kv_ws, ksum_ws);
    kernelCD6<<<dim3(16, NH_, B_), 256, 0, stream>>>(qkv, qs_arr, kv_ws, ksum_ws,
                                                     scale, w_v, b_v, w_dwc, b_dwc, out);
}